// Round 12
// baseline (142.818 us; speedup 1.0000x reference)
//
#include <hip/hip_runtime.h>
#include <hip/hip_bf16.h>
#include <stdint.h>

typedef unsigned short u16;
typedef unsigned int u32;
typedef __attribute__((ext_vector_type(8))) __bf16 bf16x8;
typedef __attribute__((ext_vector_type(4))) unsigned short us4;
typedef __attribute__((ext_vector_type(4))) float f32x4;
typedef __attribute__((ext_vector_type(16))) float f32x16;
typedef __attribute__((ext_vector_type(4))) unsigned int u32x4;
typedef __attribute__((ext_vector_type(2))) unsigned int u32x2;

#define KSCALE_Q 0.18033688011112042f  /* (1/8) * log2(e) */

#define VMCNT(n) asm volatile("s_waitcnt vmcnt(" #n ")" ::: "memory")
#define BARRIER() __builtin_amdgcn_s_barrier()

__device__ inline u16 f2bf(float f) {
  union { __bf16 b; u16 s; } x; x.b = (__bf16)f; return x.s;
}
__device__ inline u32 packbf(float a, float b) {
  return (u32)f2bf(a) | ((u32)f2bf(b) << 16);
}
__device__ inline f32x16 zero16() {
  f32x16 z; for (int i = 0; i < 16; ++i) z[i] = 0.f; return z;
}
__device__ __forceinline__ void gl_lds16(const u16* g, u16* l) {
  __builtin_amdgcn_global_load_lds(
      (const __attribute__((address_space(1))) void*)g,
      (__attribute__((address_space(3))) void*)l, 16, 0, 0);
}
__device__ __forceinline__ void pl32swap(u32& a, u32& b) {
#if __has_builtin(__builtin_amdgcn_permlane32_swap)
  u32x2 r = __builtin_amdgcn_permlane32_swap(a, b, false, false);
  a = r[0]; b = r[1];
#else
  u32 ta = (u32)__shfl_xor((int)a, 32);
  u32 tb = (u32)__shfl_xor((int)b, 32);
  int hi = (threadIdx.x & 63) >> 5;
  u32 na = hi ? tb : a;
  u32 nb = hi ? b : ta;
  a = na; b = nb;
#endif
}

// ---------------------------------------------------------------- prep (fused)
// grid 1540: [0,512) x fp32->bf16 (grid-stride, 8 float4/thread);
// [512,1536) W transposes; [1536,1540) mask scan.
__global__ __launch_bounds__(256) void prep(
    const float* __restrict__ x, const float* __restrict__ Wc,
    const float* __restrict__ Wo, const int* __restrict__ mask,
    u16* __restrict__ xbf, u16* __restrict__ wct, u16* __restrict__ wot,
    int* __restrict__ idx, int* __restrict__ nbv) {
  int r = blockIdx.x, tid = threadIdx.x;
  if (r < 512) {
#pragma unroll
    for (int t = 0; t < 8; ++t) {
      int i = (r * 8 + t) * 256 + tid;
      float4 v = ((const float4*)x)[i];
      us4 o;
      o[0] = f2bf(v.x); o[1] = f2bf(v.y); o[2] = f2bf(v.z); o[3] = f2bf(v.w);
      ((us4*)xbf)[i] = o;
    }
    return;
  }
  __shared__ float tile[32][33];
  __shared__ int ps[256];
  if (r < 1536) {
    const float* in; u16* outT; int R, C, bi;
    if (r < 1280) { in = Wc; outT = wct; R = 512; C = 1536; bi = r - 512; }
    else          { in = Wo; outT = wot; R = 512; C = 512;  bi = r - 1280; }
    int nbx = C >> 5;
    int bx = bi % nbx, by = bi / nbx;
    int xq = tid & 31, yq = tid >> 5;
    int c0 = bx * 32, r0 = by * 32;
    for (int j = 0; j < 32; j += 8)
      tile[yq + j][xq] = in[(size_t)(r0 + yq + j) * C + c0 + xq];
    __syncthreads();
    for (int j = 0; j < 32; j += 8)
      outT[(size_t)(c0 + yq + j) * R + r0 + xq] = f2bf(tile[xq][yq + j]);
    return;
  }
  int b = r - 1536;
  const int* mrow = mask + b * 2048;
  int4 a = ((const int4*)mrow)[tid * 2];
  int4 c = ((const int4*)mrow)[tid * 2 + 1];
  int v[8] = {a.x, a.y, a.z, a.w, c.x, c.y, c.z, c.w};
  int cnt = 0;
  for (int i = 0; i < 8; ++i) cnt += (v[i] > 0);
  ps[tid] = cnt;
  __syncthreads();
  for (int off = 1; off < 256; off <<= 1) {
    int xv = ps[tid];
    int yv = (tid >= off) ? ps[tid - off] : 0;
    __syncthreads();
    ps[tid] = xv + yv;
    __syncthreads();
  }
  int total = ps[255];
  int pos = ps[tid] - cnt;
  int* ip = idx + b * 2048;
  for (int i = 0; i < 8; ++i)
    if (v[i] > 0) ip[pos++] = tid * 8 + i;
  for (int i = 0; i < 8; ++i) {
    int j = tid * 8 + i;
    if (j >= total) ip[j] = 0;
  }
  if (tid == 0) nbv[b] = total;
}

// ---------------------------------------------------------------- QKV GEMM
// 128x128 tiles, BK=64, depth-1 dbuf staging (counted vmcnt).
// XCD-locality maps (assume round-robin bid->XCD):
//  Q part  [0,256): all 4 n-blocks of an A m-tile on one XCD.
//  KV part [256,768): all 8 n-blocks of a gathered (b,m) row-band on one XCD.
__global__ __launch_bounds__(256) void gemm_qkv(
    const u16* __restrict__ A, const u16* __restrict__ Bt,
    const float* __restrict__ bias, u16* __restrict__ Qc,
    u16* __restrict__ Kc, u16* __restrict__ VTc,
    const int* __restrict__ idx, const int* __restrict__ nbv) {
  const int K = 512;
  int bid = blockIdx.x;
  bool isQ = bid < 256;
  int b = 0, m0, n0;
  if (isQ) {
    int xcd = bid & 7, i = bid >> 3;       // i in [0,32)
    m0 = (xcd * 8 + (i >> 2)) * 128;       // 64 m-tiles, 8 per XCD
    n0 = (i & 3) * 128;
  } else {
    int t = bid - 256;
    int xcd = t & 7, i = t >> 3;           // i in [0,64)
    int bm = xcd + (i >> 3) * 8;           // global (b,m) in [0,64)
    b = bm >> 4;
    m0 = (bm & 15) * 128;
    n0 = (i & 7) * 128 + 512;
    int npad = (nbv[b] + 127) & ~127;
    if (m0 >= npad) return;
  }
  __shared__ __align__(16) u16 As[2][128 * 64];  // 32 KB
  __shared__ __align__(16) u16 Bs[2][128 * 64];  // 32 KB
  int tid = threadIdx.x, wave = tid >> 6, lane = tid & 63;
  int quad = lane >> 4, l16 = lane & 15;
  int wm = (wave >> 1) * 64, wn = (wave & 1) * 64;

  int r8 = lane >> 3;
  int cb = (lane & 7) ^ r8;
  const u16* agp[4];
  for (int i = 0; i < 4; ++i) {
    int row = m0 + wave * 32 + i * 8 + r8;
    int grow = isQ ? row : (b * 2048 + idx[b * 2048 + row]);
    agp[i] = A + (size_t)grow * K + cb * 8;
  }
  const u16* bg = Bt + (size_t)(n0 + wave * 32 + r8) * K + cb * 8;
  int lofs = (wave * 32) * 64 + lane * 8;

  f32x4 acc[4][4];
  for (int i = 0; i < 4; ++i)
    for (int j = 0; j < 4; ++j) acc[i][j] = (f32x4){0.f, 0.f, 0.f, 0.f};

  int rx = l16 & 7;

  auto stage = [&](int buf, int kk) {
    u16* al = As[buf] + lofs;
    u16* bl = Bs[buf] + lofs;
#pragma unroll
    for (int i = 0; i < 4; ++i)
      gl_lds16(agp[i] + kk, al + i * 8 * 64);
#pragma unroll
    for (int i = 0; i < 4; ++i)
      gl_lds16(bg + kk + (size_t)(i * 8) * K, bl + i * 8 * 64);
  };

  stage(0, 0);
  for (int t = 0; t < 8; ++t) {
    if (t < 7) { stage((t + 1) & 1, (t + 1) * 64); VMCNT(8); }
    else       { VMCNT(0); }
    BARRIER();
    const u16* Asb = As[t & 1];
    const u16* Bsb = Bs[t & 1];
#pragma unroll
    for (int ks = 0; ks < 2; ++ks) {
      int pos = ((ks * 4 + quad) ^ rx) * 8;
      bf16x8 af[4], bfr[4];
#pragma unroll
      for (int i = 0; i < 4; ++i)
        af[i] = *(const bf16x8*)(Asb + (wm + i * 16 + l16) * 64 + pos);
#pragma unroll
      for (int j = 0; j < 4; ++j)
        bfr[j] = *(const bf16x8*)(Bsb + (wn + j * 16 + l16) * 64 + pos);
#pragma unroll
      for (int i = 0; i < 4; ++i)
#pragma unroll
        for (int j = 0; j < 4; ++j)
          acc[i][j] = __builtin_amdgcn_mfma_f32_16x16x32_bf16(
              af[i], bfr[j], acc[i][j], 0, 0, 0);
    }
    BARRIER();
  }
  for (int j = 0; j < 4; ++j) {
    int col = n0 + wn + j * 16 + l16;
    float bv = bias[col];
    if (isQ) {
      for (int i = 0; i < 4; ++i) {
        int rowb = m0 + wm + i * 16 + quad * 4;
        for (int rr = 0; rr < 4; ++rr)
          Qc[(size_t)(rowb + rr) * 512 + col] =
              f2bf((acc[i][j][rr] + bv) * KSCALE_Q);
      }
    } else if (col < 1024) {  // K half
      int ck = col - 512;
      for (int i = 0; i < 4; ++i) {
        int key0 = m0 + wm + i * 16 + quad * 4;
        for (int rr = 0; rr < 4; ++rr)
          Kc[((size_t)b * 2048 + key0 + rr) * 512 + ck] =
              f2bf(acc[i][j][rr] + bv);
      }
    } else {  // V half -> transposed
      int hd = col - 1024;
      int h = hd >> 6, d = hd & 63;
      u16* vrow = VTc + ((size_t)(b * 8 + h) * 64 + d) * 2048;
      for (int i = 0; i < 4; ++i) {
        int key0 = m0 + wm + i * 16 + quad * 4;
        us4 pk;
        for (int rr = 0; rr < 4; ++rr) pk[rr] = f2bf(acc[i][j][rr] + bv);
        *(us4*)(vrow + key0) = pk;
      }
    }
  }
}

// ---------------------------------------------------------------- out GEMM
// 128x64 tiles, 512 blocks (48 KB LDS -> 3 blocks/CU; grid 2/CU so no
// residency tail), depth-1 dbuf staging with counted vmcnt, XCD-locality
// map: all 8 n-blocks of an A row-band on one XCD (A fetched once/XCD).
__global__ __launch_bounds__(256, 3) void gemm_out(
    const u16* __restrict__ A, const u16* __restrict__ Bt,
    const float* __restrict__ bias, float* __restrict__ Cout) {
  const int K = 512, N = 512;
  int bid = blockIdx.x;
  int xcd = bid & 7, i0 = bid >> 3;      // i0 in [0,64)
  int m0 = (xcd * 8 + (i0 >> 3)) * 128;  // 64 m-tiles, 8 per XCD
  int n0 = (i0 & 7) * 64;
  __shared__ __align__(16) u16 As[2][128 * 64];  // 32 KB
  __shared__ __align__(16) u16 Bs[2][64 * 64];   // 16 KB
  int tid = threadIdx.x, wave = tid >> 6, lane = tid & 63;
  int quad = lane >> 4, l16 = lane & 15;
  int wm = (wave >> 1) * 64, wn = (wave & 1) * 32;

  int r8 = lane >> 3;
  int cb = (lane & 7) ^ r8;
  const u16* ag = A + (size_t)(m0 + wave * 32 + r8) * K + cb * 8;
  const u16* bg = Bt + (size_t)(n0 + wave * 16 + r8) * K + cb * 8;
  int lofsA = (wave * 32) * 64 + lane * 8;
  int lofsB = (wave * 16) * 64 + lane * 8;

  f32x4 acc[4][2];
  for (int i = 0; i < 4; ++i)
    for (int j = 0; j < 2; ++j) acc[i][j] = (f32x4){0.f, 0.f, 0.f, 0.f};

  int rx = l16 & 7;

  auto stage = [&](int buf, int kk) {
    u16* al = As[buf] + lofsA;
    u16* bl = Bs[buf] + lofsB;
#pragma unroll
    for (int i = 0; i < 4; ++i)
      gl_lds16(ag + kk + (size_t)(i * 8) * K, al + i * 8 * 64);
#pragma unroll
    for (int i = 0; i < 2; ++i)
      gl_lds16(bg + kk + (size_t)(i * 8) * K, bl + i * 8 * 64);
  };

  stage(0, 0);
  for (int t = 0; t < 8; ++t) {
    if (t < 7) { stage((t + 1) & 1, (t + 1) * 64); VMCNT(6); }
    else       { VMCNT(0); }
    BARRIER();
    const u16* Asb = As[t & 1];
    const u16* Bsb = Bs[t & 1];
#pragma unroll
    for (int ks = 0; ks < 2; ++ks) {
      int pos = ((ks * 4 + quad) ^ rx) * 8;
      bf16x8 af[4], bfr[2];
#pragma unroll
      for (int i = 0; i < 4; ++i)
        af[i] = *(const bf16x8*)(Asb + (wm + i * 16 + l16) * 64 + pos);
#pragma unroll
      for (int j = 0; j < 2; ++j)
        bfr[j] = *(const bf16x8*)(Bsb + (wn + j * 16 + l16) * 64 + pos);
#pragma unroll
      for (int i = 0; i < 4; ++i)
#pragma unroll
        for (int j = 0; j < 2; ++j)
          acc[i][j] = __builtin_amdgcn_mfma_f32_16x16x32_bf16(
              af[i], bfr[j], acc[i][j], 0, 0, 0);
    }
    BARRIER();
  }
  for (int j = 0; j < 2; ++j) {
    int col = n0 + wn + j * 16 + l16;
    float bv = bias[col];
    for (int i = 0; i < 4; ++i) {
      int rowb = m0 + wm + i * 16 + quad * 4;
      for (int rr = 0; rr < 4; ++rr)
        Cout[(size_t)(rowb + rr) * N + col] = acc[i][j][rr] + bv;
    }
  }
}

// ---------------------------------------------------------------- attention
// v6 = r8 champion + PV accumulator chain-split: o[kp][dc] halves the
// dependent-MFMA chain depth in the PV step (8 -> 4 per tile), matching
// chain latency to issue time at 2 waves/SIMD. kp is a compile-time
// unrolled index so o stays in registers (+32 VGPR, no occupancy change;
// LDS 64 KB still governs 2 blocks/CU). Exact: disjoint partial sums
// combined once in the epilogue.
__global__ __launch_bounds__(256, 2) void attn_kernel(
    const u16* __restrict__ Qc, const u16* __restrict__ Kc,
    const u16* __restrict__ VTc, const int* __restrict__ nbv,
    u16* __restrict__ aout) {
  int flat = blockIdx.x;
  int xcd = flat & 7, ii = flat >> 3;
  int p = ((ii >> 4) << 3) | xcd;
  int c = ii & 15;
  int b = p >> 3, h = p & 7, q0 = c * 128;
  int bh = b * 8 + h;
  int tid = threadIdx.x, wave = tid >> 6, lane = tid & 63;
  int l5 = lane & 31, hi = lane >> 5;
  int nb = nbv[b];
  int npad = (nb + 127) & ~127;
  int NT = npad >> 7;

  __shared__ __align__(16) u16 Kt[2][128 * 64];  // [key][d], XOR8 16B blocks
  __shared__ __align__(16) u16 Vt[2][64 * 128];  // [d][key], XOR16 16B blocks

  bf16x8 qf[4];  // B-op: k = s*16 + hi*8 + j, n = q = l5
  int qrow = b * 2048 + q0 + wave * 32 + l5;
#pragma unroll
  for (int s = 0; s < 4; ++s)
    qf[s] = *(const bf16x8*)(Qc + (size_t)qrow * 512 + h * 64 + s * 16 +
                             hi * 8);
  VMCNT(0);  // drain qf so staging vmcnt counting is exact

  f32x16 o[2][2];  // [kp-half][dc]
#pragma unroll
  for (int kp = 0; kp < 2; ++kp)
#pragma unroll
    for (int dc = 0; dc < 2; ++dc) o[kp][dc] = zero16();
  float lsum = 0.f;

  int krr = lane >> 3;
  int kcb = (lane & 7) ^ krr;
  const u16* kg = Kc + ((size_t)(b * 2048) + wave * 32 + krr) * 512 + h * 64 +
                  kcb * 8;
  int vrr = lane >> 4;

  auto stageKV = [&](int buf, int kt0) {
    u16* kl = Kt[buf] + (wave * 32) * 64 + lane * 8;
#pragma unroll
    for (int i = 0; i < 4; ++i)
      gl_lds16(kg + (size_t)(kt0 + i * 8) * 512, kl + i * 8 * 64);
    u16* vl = Vt[buf] + (wave * 16) * 128 + lane * 8;
#pragma unroll
    for (int i = 0; i < 4; ++i) {
      int vr = wave * 16 + i * 4 + vrr;
      int vcb = (lane & 15) ^ (vr & 15);
      gl_lds16(VTc + ((size_t)(bh * 64) + vr) * 2048 + kt0 + vcb * 8,
               vl + i * 4 * 128);
    }
  };

  int rx = l5 & 7;  // (kg4*32 + l5) & 7 == l5 & 7 for all kg4
  stageKV(0, 0);
  for (int t = 0; t < NT; ++t) {
    if (t + 1 < NT) { stageKV((t + 1) & 1, (t + 1) * 128); VMCNT(8); }
    else            { VMCNT(0); }
    BARRIER();
    const u16* Ktc = Kt[t & 1];
    const u16* Vtc = Vt[t & 1];
    int kt0 = t * 128;
    bool maskT = (kt0 + 128 > nb);  // uniform: only final tile masks

#pragma unroll
    for (int kp = 0; kp < 2; ++kp) {
      bf16x8 ka[2][4];
#pragma unroll
      for (int cc = 0; cc < 2; ++cc) {
        const u16* kro = Ktc + ((kp * 2 + cc) * 32 + l5) * 64;
#pragma unroll
        for (int s = 0; s < 4; ++s)
          ka[cc][s] = *(const bf16x8*)(kro + ((s * 2 + hi) ^ rx) * 8);
      }
      f32x16 sa[2];
      sa[0] = zero16(); sa[1] = zero16();
      __builtin_amdgcn_s_setprio(1);
#pragma unroll
      for (int s = 0; s < 4; ++s) {
        sa[0] = __builtin_amdgcn_mfma_f32_32x32x16_bf16(ka[0][s], qf[s],
                                                        sa[0], 0, 0, 0);
        sa[1] = __builtin_amdgcn_mfma_f32_32x32x16_bf16(ka[1][s], qf[s],
                                                        sa[1], 0, 0, 0);
      }
      __builtin_amdgcn_s_setprio(0);
      bf16x8 pb[2][2];
#pragma unroll
      for (int cc = 0; cc < 2; ++cc) {
        int kg4 = kp * 2 + cc;
        if (maskT) {
#pragma unroll
          for (int r = 0; r < 16; ++r) {
            int jg = kt0 + kg4 * 32 + (r & 3) + 8 * (r >> 2) + 4 * hi;
            if (jg >= nb) sa[cc][r] = -1e30f;
          }
        }
        u32 pk[8];
        float ls = 0.f;
#pragma unroll
        for (int j = 0; j < 8; ++j) {
          float e0 = __builtin_amdgcn_exp2f(sa[cc][2 * j]);
          float e1 = __builtin_amdgcn_exp2f(sa[cc][2 * j + 1]);
          ls += e0 + e1;
          pk[j] = packbf(e0, e1);
        }
        lsum += ls;
#pragma unroll
        for (int t2 = 0; t2 < 2; ++t2) {
          u32 a0 = pk[t2 * 4 + 0], a2 = pk[t2 * 4 + 2];
          u32 a1 = pk[t2 * 4 + 1], a3 = pk[t2 * 4 + 3];
          pl32swap(a0, a2);
          pl32swap(a1, a3);
          u32x4 qv; qv[0] = a0; qv[1] = a1; qv[2] = a2; qv[3] = a3;
          pb[cc][t2] = __builtin_bit_cast(bf16x8, qv);
        }
      }
      __builtin_amdgcn_s_setprio(1);
#pragma unroll
      for (int cc = 0; cc < 2; ++cc) {
        int kg4 = kp * 2 + cc;
#pragma unroll
        for (int t2 = 0; t2 < 2; ++t2) {
          int cblk = kg4 * 4 + t2 * 2 + hi;
#pragma unroll
          for (int dc = 0; dc < 2; ++dc) {
            int vrow = dc * 32 + l5;
            bf16x8 va = *(const bf16x8*)(Vtc + vrow * 128 +
                                         ((cblk ^ (vrow & 15)) * 8));
            o[kp][dc] = __builtin_amdgcn_mfma_f32_32x32x16_bf16(
                va, pb[cc][t2], o[kp][dc], 0, 0, 0);
          }
        }
      }
      __builtin_amdgcn_s_setprio(0);
    }
    BARRIER();
  }

  float lt = lsum;
  lt += __shfl_xor(lt, 32);
  float inv = 1.f / lt;
#pragma unroll
  for (int dc = 0; dc < 2; ++dc)
#pragma unroll
    for (int mI = 0; mI < 4; ++mI) {
      us4 pk;
      for (int r = 0; r < 4; ++r)
        pk[r] = f2bf((o[0][dc][mI * 4 + r] + o[1][dc][mI * 4 + r]) * inv);
      *(us4*)(aout + (size_t)qrow * 512 + h * 64 + dc * 32 + mI * 8 +
              hi * 4) = pk;
    }
}

// ---------------------------------------------------------------- launch
extern "C" void kernel_launch(void* const* d_in, const int* in_sizes, int n_in,
                              void* d_out, int out_size, void* d_ws,
                              size_t ws_size, hipStream_t stream) {
  const float* x = (const float*)d_in[0];     // [4,2048,512]
  const int* mask = (const int*)d_in[1];      // [4,2048]
  const float* Wc = (const float*)d_in[2];    // [512,1536]
  const float* bc = (const float*)d_in[3];    // [1536]
  const float* Wo = (const float*)d_in[4];    // [512,512]
  const float* bo = (const float*)d_in[5];    // [512]
  float* out = (float*)d_out;                 // [4,2048,512] fp32

  char* ws = (char*)d_ws;
  u16* xbf = (u16*)(ws);                      //  8 MB [8192][512]
  u16* wct = (u16*)(ws + 8388608);            //  1.5 MB [1536][512]
  u16* wot = (u16*)(ws + 9961472);            //  0.5 MB [512][512]
  u16* Qc  = (u16*)(ws + 10485760);           //  8 MB (pre-scaled by log2e/8)
  u16* Kc  = (u16*)(ws + 18874368);           //  8 MB compact K
  u16* vtc = (u16*)(ws + 27262976);           //  8 MB compact V^T
  int* idx = (int*)(ws + 35651584);           // 32 KB
  int* nbv = (int*)(ws + 35684352);           // 16 B
  u16* aout = xbf;                            // reuse (xbf dead after gemms)

  prep<<<1540, 256, 0, stream>>>(x, Wc, Wo, mask, xbf, wct, wot, idx, nbv);
  gemm_qkv<<<768, 256, 0, stream>>>(xbf, wct, bc, Qc, Kc, vtc, idx, nbv);
  attn_kernel<<<512, 256, 0, stream>>>(Qc, Kc, vtc, nbv, aout);
  gemm_out<<<512, 256, 0, stream>>>(aout, wot, bo, out);
}

// Round 13
// 139.970 us; speedup vs baseline: 1.0203x; 1.0203x over previous
//
#include <hip/hip_runtime.h>
#include <hip/hip_bf16.h>
#include <stdint.h>

typedef unsigned short u16;
typedef unsigned int u32;
typedef __attribute__((ext_vector_type(8))) __bf16 bf16x8;
typedef __attribute__((ext_vector_type(4))) unsigned short us4;
typedef __attribute__((ext_vector_type(4))) float f32x4;
typedef __attribute__((ext_vector_type(16))) float f32x16;
typedef __attribute__((ext_vector_type(4))) unsigned int u32x4;
typedef __attribute__((ext_vector_type(2))) unsigned int u32x2;

#define KSCALE_Q 0.18033688011112042f  /* (1/8) * log2(e) */

#define VMCNT(n) asm volatile("s_waitcnt vmcnt(" #n ")" ::: "memory")
#define BARRIER() __builtin_amdgcn_s_barrier()

__device__ inline u16 f2bf(float f) {
  union { __bf16 b; u16 s; } x; x.b = (__bf16)f; return x.s;
}
__device__ inline u32 packbf(float a, float b) {
  return (u32)f2bf(a) | ((u32)f2bf(b) << 16);
}
__device__ inline f32x16 zero16() {
  f32x16 z; for (int i = 0; i < 16; ++i) z[i] = 0.f; return z;
}
__device__ __forceinline__ void gl_lds16(const u16* g, u16* l) {
  __builtin_amdgcn_global_load_lds(
      (const __attribute__((address_space(1))) void*)g,
      (__attribute__((address_space(3))) void*)l, 16, 0, 0);
}
__device__ __forceinline__ void pl32swap(u32& a, u32& b) {
#if __has_builtin(__builtin_amdgcn_permlane32_swap)
  u32x2 r = __builtin_amdgcn_permlane32_swap(a, b, false, false);
  a = r[0]; b = r[1];
#else
  u32 ta = (u32)__shfl_xor((int)a, 32);
  u32 tb = (u32)__shfl_xor((int)b, 32);
  int hi = (threadIdx.x & 63) >> 5;
  u32 na = hi ? tb : a;
  u32 nb = hi ? b : ta;
  a = na; b = nb;
#endif
}

// ---------------------------------------------------------------- prep (fused)
// grid 1540: [0,512) x fp32->bf16 (grid-stride, 8 float4/thread);
// [512,1536) W transposes; [1536,1540) mask scan.
__global__ __launch_bounds__(256) void prep(
    const float* __restrict__ x, const float* __restrict__ Wc,
    const float* __restrict__ Wo, const int* __restrict__ mask,
    u16* __restrict__ xbf, u16* __restrict__ wct, u16* __restrict__ wot,
    int* __restrict__ idx, int* __restrict__ nbv) {
  int r = blockIdx.x, tid = threadIdx.x;
  if (r < 512) {
#pragma unroll
    for (int t = 0; t < 8; ++t) {
      int i = (r * 8 + t) * 256 + tid;
      float4 v = ((const float4*)x)[i];
      us4 o;
      o[0] = f2bf(v.x); o[1] = f2bf(v.y); o[2] = f2bf(v.z); o[3] = f2bf(v.w);
      ((us4*)xbf)[i] = o;
    }
    return;
  }
  __shared__ float tile[32][33];
  __shared__ int ps[256];
  if (r < 1536) {
    const float* in; u16* outT; int R, C, bi;
    if (r < 1280) { in = Wc; outT = wct; R = 512; C = 1536; bi = r - 512; }
    else          { in = Wo; outT = wot; R = 512; C = 512;  bi = r - 1280; }
    int nbx = C >> 5;
    int bx = bi % nbx, by = bi / nbx;
    int xq = tid & 31, yq = tid >> 5;
    int c0 = bx * 32, r0 = by * 32;
    for (int j = 0; j < 32; j += 8)
      tile[yq + j][xq] = in[(size_t)(r0 + yq + j) * C + c0 + xq];
    __syncthreads();
    for (int j = 0; j < 32; j += 8)
      outT[(size_t)(c0 + yq + j) * R + r0 + xq] = f2bf(tile[xq][yq + j]);
    return;
  }
  int b = r - 1536;
  const int* mrow = mask + b * 2048;
  int4 a = ((const int4*)mrow)[tid * 2];
  int4 c = ((const int4*)mrow)[tid * 2 + 1];
  int v[8] = {a.x, a.y, a.z, a.w, c.x, c.y, c.z, c.w};
  int cnt = 0;
  for (int i = 0; i < 8; ++i) cnt += (v[i] > 0);
  ps[tid] = cnt;
  __syncthreads();
  for (int off = 1; off < 256; off <<= 1) {
    int xv = ps[tid];
    int yv = (tid >= off) ? ps[tid - off] : 0;
    __syncthreads();
    ps[tid] = xv + yv;
    __syncthreads();
  }
  int total = ps[255];
  int pos = ps[tid] - cnt;
  int* ip = idx + b * 2048;
  for (int i = 0; i < 8; ++i)
    if (v[i] > 0) ip[pos++] = tid * 8 + i;
  for (int i = 0; i < 8; ++i) {
    int j = tid * 8 + i;
    if (j >= total) ip[j] = 0;
  }
  if (tid == 0) nbv[b] = total;
}

// ---------------------------------------------------------------- QKV GEMM
// 128x128 tiles, BK=64, depth-1 dbuf staging (counted vmcnt).
// XCD-locality maps (assume round-robin bid->XCD):
//  Q part  [0,256): all 4 n-blocks of an A m-tile on one XCD.
//  KV part [256,768): all 8 n-blocks of a gathered (b,m) row-band on one XCD.
__global__ __launch_bounds__(256) void gemm_qkv(
    const u16* __restrict__ A, const u16* __restrict__ Bt,
    const float* __restrict__ bias, u16* __restrict__ Qc,
    u16* __restrict__ Kc, u16* __restrict__ VTc,
    const int* __restrict__ idx, const int* __restrict__ nbv) {
  const int K = 512;
  int bid = blockIdx.x;
  bool isQ = bid < 256;
  int b = 0, m0, n0;
  if (isQ) {
    int xcd = bid & 7, i = bid >> 3;       // i in [0,32)
    m0 = (xcd * 8 + (i >> 2)) * 128;       // 64 m-tiles, 8 per XCD
    n0 = (i & 3) * 128;
  } else {
    int t = bid - 256;
    int xcd = t & 7, i = t >> 3;           // i in [0,64)
    int bm = xcd + (i >> 3) * 8;           // global (b,m) in [0,64)
    b = bm >> 4;
    m0 = (bm & 15) * 128;
    n0 = (i & 7) * 128 + 512;
    int npad = (nbv[b] + 127) & ~127;
    if (m0 >= npad) return;
  }
  __shared__ __align__(16) u16 As[2][128 * 64];  // 32 KB
  __shared__ __align__(16) u16 Bs[2][128 * 64];  // 32 KB
  int tid = threadIdx.x, wave = tid >> 6, lane = tid & 63;
  int quad = lane >> 4, l16 = lane & 15;
  int wm = (wave >> 1) * 64, wn = (wave & 1) * 64;

  int r8 = lane >> 3;
  int cb = (lane & 7) ^ r8;
  const u16* agp[4];
  for (int i = 0; i < 4; ++i) {
    int row = m0 + wave * 32 + i * 8 + r8;
    int grow = isQ ? row : (b * 2048 + idx[b * 2048 + row]);
    agp[i] = A + (size_t)grow * K + cb * 8;
  }
  const u16* bg = Bt + (size_t)(n0 + wave * 32 + r8) * K + cb * 8;
  int lofs = (wave * 32) * 64 + lane * 8;

  f32x4 acc[4][4];
  for (int i = 0; i < 4; ++i)
    for (int j = 0; j < 4; ++j) acc[i][j] = (f32x4){0.f, 0.f, 0.f, 0.f};

  int rx = l16 & 7;

  auto stage = [&](int buf, int kk) {
    u16* al = As[buf] + lofs;
    u16* bl = Bs[buf] + lofs;
#pragma unroll
    for (int i = 0; i < 4; ++i)
      gl_lds16(agp[i] + kk, al + i * 8 * 64);
#pragma unroll
    for (int i = 0; i < 4; ++i)
      gl_lds16(bg + kk + (size_t)(i * 8) * K, bl + i * 8 * 64);
  };

  stage(0, 0);
  for (int t = 0; t < 8; ++t) {
    if (t < 7) { stage((t + 1) & 1, (t + 1) * 64); VMCNT(8); }
    else       { VMCNT(0); }
    BARRIER();
    const u16* Asb = As[t & 1];
    const u16* Bsb = Bs[t & 1];
#pragma unroll
    for (int ks = 0; ks < 2; ++ks) {
      int pos = ((ks * 4 + quad) ^ rx) * 8;
      bf16x8 af[4], bfr[4];
#pragma unroll
      for (int i = 0; i < 4; ++i)
        af[i] = *(const bf16x8*)(Asb + (wm + i * 16 + l16) * 64 + pos);
#pragma unroll
      for (int j = 0; j < 4; ++j)
        bfr[j] = *(const bf16x8*)(Bsb + (wn + j * 16 + l16) * 64 + pos);
#pragma unroll
      for (int i = 0; i < 4; ++i)
#pragma unroll
        for (int j = 0; j < 4; ++j)
          acc[i][j] = __builtin_amdgcn_mfma_f32_16x16x32_bf16(
              af[i], bfr[j], acc[i][j], 0, 0, 0);
    }
    BARRIER();
  }
  for (int j = 0; j < 4; ++j) {
    int col = n0 + wn + j * 16 + l16;
    float bv = bias[col];
    if (isQ) {
      for (int i = 0; i < 4; ++i) {
        int rowb = m0 + wm + i * 16 + quad * 4;
        for (int rr = 0; rr < 4; ++rr)
          Qc[(size_t)(rowb + rr) * 512 + col] =
              f2bf((acc[i][j][rr] + bv) * KSCALE_Q);
      }
    } else if (col < 1024) {  // K half
      int ck = col - 512;
      for (int i = 0; i < 4; ++i) {
        int key0 = m0 + wm + i * 16 + quad * 4;
        for (int rr = 0; rr < 4; ++rr)
          Kc[((size_t)b * 2048 + key0 + rr) * 512 + ck] =
              f2bf(acc[i][j][rr] + bv);
      }
    } else {  // V half -> transposed
      int hd = col - 1024;
      int h = hd >> 6, d = hd & 63;
      u16* vrow = VTc + ((size_t)(b * 8 + h) * 64 + d) * 2048;
      for (int i = 0; i < 4; ++i) {
        int key0 = m0 + wm + i * 16 + quad * 4;
        us4 pk;
        for (int rr = 0; rr < 4; ++rr) pk[rr] = f2bf(acc[i][j][rr] + bv);
        *(us4*)(vrow + key0) = pk;
      }
    }
  }
}

// ---------------------------------------------------------------- out GEMM
// 128x64 tiles, 512 blocks (48 KB LDS -> 3 blocks/CU; grid 2/CU so no
// residency tail), depth-1 dbuf staging with counted vmcnt, XCD-locality
// map: all 8 n-blocks of an A row-band on one XCD (A fetched once/XCD).
__global__ __launch_bounds__(256, 3) void gemm_out(
    const u16* __restrict__ A, const u16* __restrict__ Bt,
    const float* __restrict__ bias, float* __restrict__ Cout) {
  const int K = 512, N = 512;
  int bid = blockIdx.x;
  int xcd = bid & 7, i0 = bid >> 3;      // i0 in [0,64)
  int m0 = (xcd * 8 + (i0 >> 3)) * 128;  // 64 m-tiles, 8 per XCD
  int n0 = (i0 & 7) * 64;
  __shared__ __align__(16) u16 As[2][128 * 64];  // 32 KB
  __shared__ __align__(16) u16 Bs[2][64 * 64];   // 16 KB
  int tid = threadIdx.x, wave = tid >> 6, lane = tid & 63;
  int quad = lane >> 4, l16 = lane & 15;
  int wm = (wave >> 1) * 64, wn = (wave & 1) * 32;

  int r8 = lane >> 3;
  int cb = (lane & 7) ^ r8;
  const u16* ag = A + (size_t)(m0 + wave * 32 + r8) * K + cb * 8;
  const u16* bg = Bt + (size_t)(n0 + wave * 16 + r8) * K + cb * 8;
  int lofsA = (wave * 32) * 64 + lane * 8;
  int lofsB = (wave * 16) * 64 + lane * 8;

  f32x4 acc[4][2];
  for (int i = 0; i < 4; ++i)
    for (int j = 0; j < 2; ++j) acc[i][j] = (f32x4){0.f, 0.f, 0.f, 0.f};

  int rx = l16 & 7;

  auto stage = [&](int buf, int kk) {
    u16* al = As[buf] + lofsA;
    u16* bl = Bs[buf] + lofsB;
#pragma unroll
    for (int i = 0; i < 4; ++i)
      gl_lds16(ag + kk + (size_t)(i * 8) * K, al + i * 8 * 64);
#pragma unroll
    for (int i = 0; i < 2; ++i)
      gl_lds16(bg + kk + (size_t)(i * 8) * K, bl + i * 8 * 64);
  };

  stage(0, 0);
  for (int t = 0; t < 8; ++t) {
    if (t < 7) { stage((t + 1) & 1, (t + 1) * 64); VMCNT(6); }
    else       { VMCNT(0); }
    BARRIER();
    const u16* Asb = As[t & 1];
    const u16* Bsb = Bs[t & 1];
#pragma unroll
    for (int ks = 0; ks < 2; ++ks) {
      int pos = ((ks * 4 + quad) ^ rx) * 8;
      bf16x8 af[4], bfr[2];
#pragma unroll
      for (int i = 0; i < 4; ++i)
        af[i] = *(const bf16x8*)(Asb + (wm + i * 16 + l16) * 64 + pos);
#pragma unroll
      for (int j = 0; j < 2; ++j)
        bfr[j] = *(const bf16x8*)(Bsb + (wn + j * 16 + l16) * 64 + pos);
#pragma unroll
      for (int i = 0; i < 4; ++i)
#pragma unroll
        for (int j = 0; j < 2; ++j)
          acc[i][j] = __builtin_amdgcn_mfma_f32_16x16x32_bf16(
              af[i], bfr[j], acc[i][j], 0, 0, 0);
    }
    BARRIER();
  }
  for (int j = 0; j < 2; ++j) {
    int col = n0 + wn + j * 16 + l16;
    float bv = bias[col];
    for (int i = 0; i < 4; ++i) {
      int rowb = m0 + wm + i * 16 + quad * 4;
      for (int rr = 0; rr < 4; ++rr)
        Cout[(size_t)(rowb + rr) * N + col] = acc[i][j][rr] + bv;
    }
  }
}

// ---------------------------------------------------------------- attention
// v4 (champion, r8/r11): 512 blocks x 4 waves, 128 q rows/block (32 q/wave),
// KVBLK=128, LDS 64 KB -> 2 blocks/CU, dual k-group MFMA chains,
// XCD-locality remap, depth-1 dbuf staging (counted vmcnt), setprio.
__global__ __launch_bounds__(256, 2) void attn_kernel(
    const u16* __restrict__ Qc, const u16* __restrict__ Kc,
    const u16* __restrict__ VTc, const int* __restrict__ nbv,
    u16* __restrict__ aout) {
  int flat = blockIdx.x;
  int xcd = flat & 7, ii = flat >> 3;
  int p = ((ii >> 4) << 3) | xcd;
  int c = ii & 15;
  int b = p >> 3, h = p & 7, q0 = c * 128;
  int bh = b * 8 + h;
  int tid = threadIdx.x, wave = tid >> 6, lane = tid & 63;
  int l5 = lane & 31, hi = lane >> 5;
  int nb = nbv[b];
  int npad = (nb + 127) & ~127;
  int NT = npad >> 7;

  __shared__ __align__(16) u16 Kt[2][128 * 64];  // [key][d], XOR8 16B blocks
  __shared__ __align__(16) u16 Vt[2][64 * 128];  // [d][key], XOR16 16B blocks

  bf16x8 qf[4];  // B-op: k = s*16 + hi*8 + j, n = q = l5
  int qrow = b * 2048 + q0 + wave * 32 + l5;
#pragma unroll
  for (int s = 0; s < 4; ++s)
    qf[s] = *(const bf16x8*)(Qc + (size_t)qrow * 512 + h * 64 + s * 16 +
                             hi * 8);
  VMCNT(0);  // drain qf so staging vmcnt counting is exact

  f32x16 o[2];
  o[0] = zero16(); o[1] = zero16();
  float lsum = 0.f;

  int krr = lane >> 3;
  int kcb = (lane & 7) ^ krr;
  const u16* kg = Kc + ((size_t)(b * 2048) + wave * 32 + krr) * 512 + h * 64 +
                  kcb * 8;
  int vrr = lane >> 4;

  auto stageKV = [&](int buf, int kt0) {
    u16* kl = Kt[buf] + (wave * 32) * 64 + lane * 8;
#pragma unroll
    for (int i = 0; i < 4; ++i)
      gl_lds16(kg + (size_t)(kt0 + i * 8) * 512, kl + i * 8 * 64);
    u16* vl = Vt[buf] + (wave * 16) * 128 + lane * 8;
#pragma unroll
    for (int i = 0; i < 4; ++i) {
      int vr = wave * 16 + i * 4 + vrr;
      int vcb = (lane & 15) ^ (vr & 15);
      gl_lds16(VTc + ((size_t)(bh * 64) + vr) * 2048 + kt0 + vcb * 8,
               vl + i * 4 * 128);
    }
  };

  int rx = l5 & 7;  // (kg4*32 + l5) & 7 == l5 & 7 for all kg4
  stageKV(0, 0);
  for (int t = 0; t < NT; ++t) {
    if (t + 1 < NT) { stageKV((t + 1) & 1, (t + 1) * 128); VMCNT(8); }
    else            { VMCNT(0); }
    BARRIER();
    const u16* Ktc = Kt[t & 1];
    const u16* Vtc = Vt[t & 1];
    int kt0 = t * 128;
    bool maskT = (kt0 + 128 > nb);  // uniform: only final tile masks

#pragma unroll
    for (int kp = 0; kp < 2; ++kp) {
      bf16x8 ka[2][4];
#pragma unroll
      for (int cc = 0; cc < 2; ++cc) {
        const u16* kro = Ktc + ((kp * 2 + cc) * 32 + l5) * 64;
#pragma unroll
        for (int s = 0; s < 4; ++s)
          ka[cc][s] = *(const bf16x8*)(kro + ((s * 2 + hi) ^ rx) * 8);
      }
      f32x16 sa[2];
      sa[0] = zero16(); sa[1] = zero16();
      __builtin_amdgcn_s_setprio(1);
#pragma unroll
      for (int s = 0; s < 4; ++s) {
        sa[0] = __builtin_amdgcn_mfma_f32_32x32x16_bf16(ka[0][s], qf[s],
                                                        sa[0], 0, 0, 0);
        sa[1] = __builtin_amdgcn_mfma_f32_32x32x16_bf16(ka[1][s], qf[s],
                                                        sa[1], 0, 0, 0);
      }
      __builtin_amdgcn_s_setprio(0);
      bf16x8 pb[2][2];
#pragma unroll
      for (int cc = 0; cc < 2; ++cc) {
        int kg4 = kp * 2 + cc;
        if (maskT) {
#pragma unroll
          for (int r = 0; r < 16; ++r) {
            int jg = kt0 + kg4 * 32 + (r & 3) + 8 * (r >> 2) + 4 * hi;
            if (jg >= nb) sa[cc][r] = -1e30f;
          }
        }
        u32 pk[8];
        float ls = 0.f;
#pragma unroll
        for (int j = 0; j < 8; ++j) {
          float e0 = __builtin_amdgcn_exp2f(sa[cc][2 * j]);
          float e1 = __builtin_amdgcn_exp2f(sa[cc][2 * j + 1]);
          ls += e0 + e1;
          pk[j] = packbf(e0, e1);
        }
        lsum += ls;
#pragma unroll
        for (int t2 = 0; t2 < 2; ++t2) {
          u32 a0 = pk[t2 * 4 + 0], a2 = pk[t2 * 4 + 2];
          u32 a1 = pk[t2 * 4 + 1], a3 = pk[t2 * 4 + 3];
          pl32swap(a0, a2);
          pl32swap(a1, a3);
          u32x4 qv; qv[0] = a0; qv[1] = a1; qv[2] = a2; qv[3] = a3;
          pb[cc][t2] = __builtin_bit_cast(bf16x8, qv);
        }
      }
      __builtin_amdgcn_s_setprio(1);
#pragma unroll
      for (int cc = 0; cc < 2; ++cc) {
        int kg4 = kp * 2 + cc;
#pragma unroll
        for (int t2 = 0; t2 < 2; ++t2) {
          int cblk = kg4 * 4 + t2 * 2 + hi;
#pragma unroll
          for (int dc = 0; dc < 2; ++dc) {
            int vrow = dc * 32 + l5;
            bf16x8 va = *(const bf16x8*)(Vtc + vrow * 128 +
                                         ((cblk ^ (vrow & 15)) * 8));
            o[dc] = __builtin_amdgcn_mfma_f32_32x32x16_bf16(
                va, pb[cc][t2], o[dc], 0, 0, 0);
          }
        }
      }
      __builtin_amdgcn_s_setprio(0);
    }
    BARRIER();
  }

  float lt = lsum;
  lt += __shfl_xor(lt, 32);
  float inv = 1.f / lt;
#pragma unroll
  for (int dc = 0; dc < 2; ++dc)
#pragma unroll
    for (int mI = 0; mI < 4; ++mI) {
      us4 pk;
      for (int r = 0; r < 4; ++r) pk[r] = f2bf(o[dc][mI * 4 + r] * inv);
      *(us4*)(aout + (size_t)qrow * 512 + h * 64 + dc * 32 + mI * 8 +
              hi * 4) = pk;
    }
}

// ---------------------------------------------------------------- launch
extern "C" void kernel_launch(void* const* d_in, const int* in_sizes, int n_in,
                              void* d_out, int out_size, void* d_ws,
                              size_t ws_size, hipStream_t stream) {
  const float* x = (const float*)d_in[0];     // [4,2048,512]
  const int* mask = (const int*)d_in[1];      // [4,2048]
  const float* Wc = (const float*)d_in[2];    // [512,1536]
  const float* bc = (const float*)d_in[3];    // [1536]
  const float* Wo = (const float*)d_in[4];    // [512,512]
  const float* bo = (const float*)d_in[5];    // [512]
  float* out = (float*)d_out;                 // [4,2048,512] fp32

  char* ws = (char*)d_ws;
  u16* xbf = (u16*)(ws);                      //  8 MB [8192][512]
  u16* wct = (u16*)(ws + 8388608);            //  1.5 MB [1536][512]
  u16* wot = (u16*)(ws + 9961472);            //  0.5 MB [512][512]
  u16* Qc  = (u16*)(ws + 10485760);           //  8 MB (pre-scaled by log2e/8)
  u16* Kc  = (u16*)(ws + 18874368);           //  8 MB compact K
  u16* vtc = (u16*)(ws + 27262976);           //  8 MB compact V^T
  int* idx = (int*)(ws + 35651584);           // 32 KB
  int* nbv = (int*)(ws + 35684352);           // 16 B
  u16* aout = xbf;                            // reuse (xbf dead after gemms)

  prep<<<1540, 256, 0, stream>>>(x, Wc, Wo, mask, xbf, wct, wot, idx, nbv);
  gemm_qkv<<<768, 256, 0, stream>>>(xbf, wct, bc, Qc, Kc, vtc, idx, nbv);
  attn_kernel<<<512, 256, 0, stream>>>(Qc, Kc, vtc, nbv, aout);
  gemm_out<<<512, 256, 0, stream>>>(aout, wot, bo, out);
}